// Round 15
// baseline (769.276 us; speedup 1.0000x reference)
//
#include <hip/hip_runtime.h>
#include <hip/hip_bf16.h>

// N=8192, D=512.  Q = emb@Wqk^T+bqk (K==Q); out = softmax(QK^T/sqrt(512)) @ V.
// Softmax rows sum to 1 => out = (softmax(S)@emb) @ Wv^T + bv (V never built).
// Device dtype runtime-detected (fp32 observed). Internal: bf16 MFMA, fp32 acc.
// R14 post-mortem: attn64 pinned at traffic wall (2.05GB @ 7.2TB/s). The R9
// Tq=128 spill was SELF-INFLICTED (__launch_bounds__(512,2) forced a 128-VGPR
// cap); a plain 512-thr block gets 256 VGPRs. R15: attn128 = R12's
// correctness-proven structure at 512thr/8 waves (wave: S for 16 keys x 128
// rows; owns 64 D-cols in PV; accO[8][4]=128 + accS 32 + lsum 32 ~ 230 <= 256).
// Grid 256 = 64 q-tiles x 4 key-splits -> traffic 1.06 GB (half of R13/14).
// 4 bf16 partials, finalize 4-way merge. Satellites unchanged from R14.

#define NTOK 8192
#define DIM  512

typedef unsigned short ushort_t;
typedef __attribute__((ext_vector_type(8))) __bf16 bf16x8;
typedef __attribute__((ext_vector_type(4))) float f32x4;

__device__ __forceinline__ float bf2f(ushort_t u) {
    union { unsigned int i; float f; } v; v.i = ((unsigned int)u) << 16; return v.f;
}
__device__ __forceinline__ ushort_t f2bf(float f) {
    union { float f; unsigned int i; } v; v.f = f;
    unsigned int b = v.i;
    return (ushort_t)((b + 0x7FFFu + ((b >> 16) & 1u)) >> 16);   // RNE
}
__device__ __forceinline__ __bf16 f2bfh(float f) {
    union { ushort_t u; __bf16 h; } c; c.u = f2bf(f); return c.h;
}
__device__ __forceinline__ f32x4 mfma16(bf16x8 a, bf16x8 b, f32x4 c) {
    return __builtin_amdgcn_mfma_f32_16x16x32_bf16(a, b, c, 0, 0, 0);
}
__device__ __forceinline__ bf16x8 load8(const void* p, size_t idx, bool f32) {
    if (f32) {
        const float* f = (const float*)p + idx;
        bf16x8 r;
        #pragma unroll
        for (int j = 0; j < 8; ++j) r[j] = f2bfh(f[j]);
        return r;
    }
    return *(const bf16x8*)((const ushort_t*)p + idx);
}
__device__ __forceinline__ float loadS(const void* p, size_t idx, bool f32) {
    return f32 ? ((const float*)p)[idx] : bf2f(((const ushort_t*)p)[idx]);
}

#define LDA 520   // 260 dw, %32=4: uniform 2 dw/bank for b128 row reads
#define LDP 264

// ---------------------------------------------------------------------------
// Dtype probe: flag=1 => bf16 data, flag=0 => fp32.
// ---------------------------------------------------------------------------
__global__ void detect_kernel(const ushort_t* __restrict__ emb, int* __restrict__ flag)
{
    int lane = threadIdx.x;
    int cnt = 0;
    #pragma unroll
    for (int i = 0; i < 8; ++i) {
        ushort_t u = emb[(size_t)(lane * 8 + i) * 2];
        int a = u & 0x7FFF;
        int e = (u >> 7) & 0xFF;
        if (a == 0 || (e >= 111 && e <= 143)) cnt++;
    }
    cnt += __shfl_xor(cnt, 1);  cnt += __shfl_xor(cnt, 2);  cnt += __shfl_xor(cnt, 4);
    cnt += __shfl_xor(cnt, 8);  cnt += __shfl_xor(cnt, 16); cnt += __shfl_xor(cnt, 32);
    if (lane == 0) *flag = (cnt >= 460) ? 1 : 0;
}

// ---------------------------------------------------------------------------
// Prep: convert Wqk, Wv (512x512) + bqk, bv (512) to bf16 in ws.
// ---------------------------------------------------------------------------
__global__ __launch_bounds__(256)
void prep_kernel(const int* __restrict__ flag,
                 const void* __restrict__ Wqk, const void* __restrict__ bqk,
                 const void* __restrict__ Wv,  const void* __restrict__ bv,
                 ushort_t* __restrict__ Wqkb, ushort_t* __restrict__ bqkb,
                 ushort_t* __restrict__ Wvb,  ushort_t* __restrict__ bvb)
{
    const bool f32 = (*flag == 0);
    size_t gid = (size_t)blockIdx.x * 256 + threadIdx.x;
    size_t base = gid * 8;
    *(bf16x8*)&Wqkb[base] = load8(Wqk, base, f32);
    *(bf16x8*)&Wvb[base]  = load8(Wv,  base, f32);
    if (gid < 64) {
        *(bf16x8*)&bqkb[base] = load8(bqk, base, f32);
        *(bf16x8*)&bvb[base]  = load8(bv,  base, f32);
    }
}

// ---------------------------------------------------------------------------
// Fused: Q[64 rows] = emb@Wqk^T+bqk AND embT columns (R14-proven).
// 128 blocks x 512 thr (8 waves).
// ---------------------------------------------------------------------------
__global__ __launch_bounds__(512)
void projqT_kernel(const int* __restrict__ flag, const void* __restrict__ emb,
                   const ushort_t* __restrict__ Wb, const ushort_t* __restrict__ bb,
                   ushort_t* __restrict__ C, ushort_t* __restrict__ embT)
{
    __shared__ ushort_t Alds[64][LDA];
    const bool f32 = (*flag == 0);
    const int tid  = threadIdx.x;
    const int wave = tid >> 6;
    const int lane = tid & 63;
    const int quad = lane >> 4;
    const int col  = lane & 15;
    const int mblk = blockIdx.x * 64;

    #pragma unroll
    for (int i = 0; i < 8; ++i) {
        int chunk = i * 512 + tid;
        int row = chunk >> 6;
        int k8  = (chunk & 63) * 8;
        *(bf16x8*)&Alds[row][k8] = load8(emb, (size_t)(mblk + row) * 512 + k8, f32);
    }
    __syncthreads();

    {
        ushort_t buf[64];
        #pragma unroll
        for (int r = 0; r < 64; ++r) buf[r] = Alds[r][tid];
        ushort_t* dst = embT + (size_t)tid * NTOK + mblk;
        #pragma unroll
        for (int i = 0; i < 8; ++i)
            *(uint4*)(dst + i * 8) = *(uint4*)&buf[i * 8];
    }

    f32x4 acc[4][4];
    #pragma unroll
    for (int r = 0; r < 4; ++r)
        #pragma unroll
        for (int c = 0; c < 4; ++c) acc[r][c] = (f32x4){0.f, 0.f, 0.f, 0.f};

    const int wcol = wave * 64;
    #pragma unroll
    for (int kk = 0; kk < 16; ++kk) {
        bf16x8 a[4];
        #pragma unroll
        for (int r = 0; r < 4; ++r)
            a[r] = *(const bf16x8*)&Alds[r * 16 + col][kk * 32 + quad * 8];
        #pragma unroll
        for (int c = 0; c < 4; ++c) {
            bf16x8 b = *(const bf16x8*)&Wb[(size_t)(wcol + c * 16 + col) * 512
                                           + kk * 32 + quad * 8];
            #pragma unroll
            for (int r = 0; r < 4; ++r)
                acc[r][c] = mfma16(a[r], b, acc[r][c]);
        }
    }

    #pragma unroll
    for (int r = 0; r < 4; ++r)
        #pragma unroll
        for (int c = 0; c < 4; ++c)
            #pragma unroll
            for (int g = 0; g < 4; ++g) {
                int m = mblk + r * 16 + quad * 4 + g;
                int n = wcol + c * 16 + col;
                C[(size_t)m * DIM + n] = f2bf(acc[r][c][g] + bf2f(bb[n]));
            }
}

// ---------------------------------------------------------------------------
// Attention partials, Tq=128 @ 512 thr (full 256-VGPR budget, 1 block/CU).
// Grid 256 = 64 q-tiles x 4 key-splits (2048 keys), 8 waves, KT=128 (16 iters).
// Wave w: S for keys [16w,16w+16) x all 128 rows (accS[8]); owns D cols
// [64w,64w+64) in PV (accO[8][4]). Qlds 128KB XOR-swizzled + Plds 16KB
// two-phase (R12-verified layouts). bf16 partials, LDS lsum reduce, no atomics.
// ---------------------------------------------------------------------------
__global__ __launch_bounds__(512)
void attn128_kernel(const ushort_t* __restrict__ Q, const ushort_t* __restrict__ embT,
                    ushort_t* __restrict__ Pall, float* __restrict__ lsumA)
{
    __shared__ ushort_t Qlds[128 * 512];   // 131,072 B, swizzled chunk^(row&7)
    __shared__ ushort_t Plds[128 * 64];    //  16,384 B, one 64-key phase
    __shared__ float    Lp[8][128];        //   4,096 B  -> 151,552 B total

    const int tid  = threadIdx.x;
    const int wave = tid >> 6;
    const int lane = tid & 63;
    const int quad = lane >> 4;
    const int col  = lane & 15;
    const int qt   = blockIdx.x >> 2;
    const int ks   = blockIdx.x & 3;
    const int q0   = qt * 128;
    const int kb0  = ks * 2048;
    ushort_t* Ps = Pall + (size_t)ks * NTOK * DIM;

    {   // stage Q tile 128x512 bf16 swizzled (R9/R12 staging, 512 thr)
        const int srow = tid >> 2, scb = (tid & 3) * 16;
        const ushort_t* src = &Q[(size_t)(q0 + srow) * 512];
        ushort_t* dstrow = &Qlds[srow * 512];
        const int sw = (srow & 7) * 8;
        #pragma unroll
        for (int i = 0; i < 16; ++i) {
            int c8 = (scb + i) * 8;
            *(bf16x8*)&dstrow[c8 ^ sw] = *(const bf16x8*)&src[c8];
        }
    }
    __syncthreads();

    f32x4 accO[8][4];
    #pragma unroll
    for (int r = 0; r < 8; ++r)
        #pragma unroll
        for (int c = 0; c < 4; ++c) accO[r][c] = (f32x4){0.f, 0.f, 0.f, 0.f};

    float lsum[8][4];
    #pragma unroll
    for (int r = 0; r < 8; ++r)
        #pragma unroll
        for (int g = 0; g < 4; ++g) lsum[r][g] = 0.f;

    const float sc = 0.04419417382415922f * 1.4426950408889634f;  // 1/sqrt(512)*log2e
    const int wd = wave * 64;            // owned D-col base in PV
    const int colsw = (col & 7) * 8;

    for (int it = 0; it < 16; ++it) {
        const int j0 = kb0 + it * 128;

        // ---- S(128 rows x this wave's 16 keys), kb 2-at-a-time ----
        f32x4 accS[8];
        #pragma unroll
        for (int r = 0; r < 8; ++r) accS[r] = (f32x4){0.f, 0.f, 0.f, 0.f};
        const size_t keyrow = (size_t)(j0 + wave * 16 + col) * 512;
        #pragma unroll
        for (int kc2 = 0; kc2 < 8; ++kc2) {
            bf16x8 kA = *(const bf16x8*)&Q[keyrow + (kc2 * 2) * 32 + quad * 8];
            bf16x8 kB = *(const bf16x8*)&Q[keyrow + (kc2 * 2 + 1) * 32 + quad * 8];
            #pragma unroll
            for (int k = 0; k < 2; ++k) {
                const int cofs = (kc2 * 2 + k) * 32 + quad * 8;
                bf16x8 kb8 = k ? kB : kA;
                #pragma unroll
                for (int r = 0; r < 8; ++r) {
                    bf16x8 a = *(const bf16x8*)&Qlds[(r * 16 + col) * 512 + (cofs ^ colsw)];
                    accS[r] = mfma16(a, kb8, accS[r]);
                }
            }
        }

        // ---- P = exp2(S*sc) in-register; accumulate row sums ----
        #pragma unroll
        for (int r = 0; r < 8; ++r)
            #pragma unroll
            for (int g = 0; g < 4; ++g) {
                float v = exp2f(fminf(accS[r][g] * sc, 126.0f));
                accS[r][g] = v;
                lsum[r][g] += v;
            }

        // ---- two 64-key phases (R12-verified layout) ----
        #pragma unroll
        for (int ph = 0; ph < 2; ++ph) {
            if ((wave >> 2) == ph) {
                const int klb = (wave & 3) * 16;
                #pragma unroll
                for (int r = 0; r < 8; ++r)
                    #pragma unroll
                    for (int g = 0; g < 4; ++g) {
                        int prow = r * 16 + quad * 4 + g;
                        int kl   = klb + col;
                        int kch  = kl >> 3;
                        Plds[prow * 64 + (((kch ^ (prow & 7)) << 3) | (kl & 7))]
                            = f2bf(accS[r][g]);
                    }
            }
            __syncthreads();   // P(phase) visible; protects prior-phase reads

            #pragma unroll
            for (int kf = 0; kf < 2; ++kf) {
                const size_t kgl = (size_t)j0 + ph * 64 + kf * 32 + quad * 8;
                bf16x8 vb[4];
                #pragma unroll
                for (int c = 0; c < 4; ++c)
                    vb[c] = *(const bf16x8*)&embT[(size_t)(wd + c * 16 + col) * NTOK + kgl];
                #pragma unroll
                for (int r = 0; r < 8; ++r) {
                    int prow = r * 16 + col;
                    bf16x8 a = *(const bf16x8*)&Plds[prow * 64
                                  + (((kf * 4 + quad) ^ (prow & 7)) << 3)];
                    #pragma unroll
                    for (int c = 0; c < 4; ++c)
                        accO[r][c] = mfma16(a, vb[c], accO[r][c]);
                }
            }
            __syncthreads();   // PV reads done before next phase overwrites Plds
        }
    }

    // ---- row sums: lane-reduce (16 key-lanes) then cross-wave LDS reduce ----
    #pragma unroll
    for (int r = 0; r < 8; ++r)
        #pragma unroll
        for (int g = 0; g < 4; ++g) {
            float s = lsum[r][g];
            s += __shfl_xor(s, 1);
            s += __shfl_xor(s, 2);
            s += __shfl_xor(s, 4);
            s += __shfl_xor(s, 8);
            if (col == 0)
                Lp[wave][r * 16 + quad * 4 + g] = s;
        }
    __syncthreads();
    if (tid < 128) {
        float t = 0.f;
        #pragma unroll
        for (int w = 0; w < 8; ++w) t += Lp[w][tid];
        lsumA[(size_t)ks * NTOK + q0 + tid] = t;
    }

    // ---- bf16 partial store (disjoint, full 128x512 coverage) ----
    #pragma unroll
    for (int r = 0; r < 8; ++r)
        #pragma unroll
        for (int c = 0; c < 4; ++c)
            #pragma unroll
            for (int g = 0; g < 4; ++g)
                Ps[(size_t)(q0 + r * 16 + quad * 4 + g) * DIM + wd + c * 16 + col]
                    = f2bf(accO[r][c][g]);
}

// ---------------------------------------------------------------------------
// Finalize: T = (sum of 4 bf16 partials)/(sum of 4 lsums), out = T@Wv^T+bv.
// 128 blocks x 512 thr, 64 rows/block (R14 structure, 4-way merge).
// ---------------------------------------------------------------------------
__global__ __launch_bounds__(512)
void finalize_kernel(const int* __restrict__ flag, const ushort_t* __restrict__ Pall,
                     const float* __restrict__ lsumA,
                     const ushort_t* __restrict__ Wb, const ushort_t* __restrict__ bb,
                     void* __restrict__ Out)
{
    __shared__ ushort_t Alds[64][LDA];
    const bool f32 = (*flag == 0);
    const int tid  = threadIdx.x;
    const int wave = tid >> 6;
    const int lane = tid & 63;
    const int quad = lane >> 4;
    const int col  = lane & 15;
    const int mblk = blockIdx.x * 64;

    #pragma unroll
    for (int i = 0; i < 8; ++i) {
        int chunk = i * 512 + tid;
        int row = chunk >> 6;
        int k8  = (chunk & 63) * 8;
        int m   = mblk + row;
        float rv = 1.0f / (lsumA[m] + lsumA[NTOK + m] + lsumA[2 * NTOK + m]
                           + lsumA[3 * NTOK + m]);
        float s[8];
        #pragma unroll
        for (int j = 0; j < 8; ++j) s[j] = 0.f;
        #pragma unroll
        for (int t = 0; t < 4; ++t) {
            bf16x8 v = *(const bf16x8*)&Pall[(size_t)t * NTOK * DIM + (size_t)m * 512 + k8];
            #pragma unroll
            for (int j = 0; j < 8; ++j) s[j] += (float)v[j];
        }
        bf16x8 o;
        #pragma unroll
        for (int j = 0; j < 8; ++j) o[j] = f2bfh(s[j] * rv);
        *(bf16x8*)&Alds[row][k8] = o;
    }
    __syncthreads();

    f32x4 acc[4][4];
    #pragma unroll
    for (int r = 0; r < 4; ++r)
        #pragma unroll
        for (int c = 0; c < 4; ++c) acc[r][c] = (f32x4){0.f, 0.f, 0.f, 0.f};

    const int wcol = wave * 64;
    #pragma unroll
    for (int kk = 0; kk < 16; ++kk) {
        bf16x8 a[4];
        #pragma unroll
        for (int r = 0; r < 4; ++r)
            a[r] = *(const bf16x8*)&Alds[r * 16 + col][kk * 32 + quad * 8];
        #pragma unroll
        for (int c = 0; c < 4; ++c) {
            bf16x8 b = *(const bf16x8*)&Wb[(size_t)(wcol + c * 16 + col) * 512
                                           + kk * 32 + quad * 8];
            #pragma unroll
            for (int r = 0; r < 4; ++r)
                acc[r][c] = mfma16(a[r], b, acc[r][c]);
        }
    }

    #pragma unroll
    for (int r = 0; r < 4; ++r)
        #pragma unroll
        for (int c = 0; c < 4; ++c)
            #pragma unroll
            for (int g = 0; g < 4; ++g) {
                int m = mblk + r * 16 + quad * 4 + g;
                int n = wcol + c * 16 + col;
                float v = acc[r][c][g] + bf2f(bb[n]);
                if (f32) ((float*)Out)[(size_t)m * DIM + n] = v;
                else     ((ushort_t*)Out)[(size_t)m * DIM + n] = f2bf(v);
            }
}

// ---------------------------------------------------------------------------
// Fallback kernels (R13/R14-proven) for smaller workspaces.
// ---------------------------------------------------------------------------
__global__ __launch_bounds__(256)
void transpose_kernel(const int* __restrict__ flag, const void* __restrict__ emb,
                      ushort_t* __restrict__ embT)
{
    __shared__ float tile[64][65];
    const bool f32 = (*flag == 0);
    const int t  = threadIdx.x;
    const int j0 = blockIdx.x * 64;
    const int d0 = blockIdx.y * 64;
    {
        int r = t >> 2, cs = (t & 3) * 16;
        if (f32) {
            const float* src = (const float*)emb + (size_t)(j0 + r) * DIM + d0 + cs;
            #pragma unroll
            for (int i = 0; i < 16; i += 4) {
                float4 v = *(const float4*)(src + i);
                tile[r][cs + i]     = v.x;
                tile[r][cs + i + 1] = v.y;
                tile[r][cs + i + 2] = v.z;
                tile[r][cs + i + 3] = v.w;
            }
        } else {
            const ushort_t* src = (const ushort_t*)emb + (size_t)(j0 + r) * DIM + d0 + cs;
            #pragma unroll
            for (int i = 0; i < 16; ++i) tile[r][cs + i] = bf2f(src[i]);
        }
    }
    __syncthreads();
    {
        int d = t >> 2, js = (t & 3) * 16;
        ushort_t buf[16];
        #pragma unroll
        for (int i = 0; i < 16; ++i) buf[i] = f2bf(tile[js + i][d]);
        ushort_t* dst = embT + (size_t)(d0 + d) * NTOK + j0 + js;
        *(uint4*)dst       = *(uint4*)&buf[0];
        *(uint4*)(dst + 8) = *(uint4*)&buf[8];
    }
}

__global__ __launch_bounds__(512)
void projq_kernel(const int* __restrict__ flag, const void* __restrict__ emb,
                  const void* __restrict__ W, const void* __restrict__ bias,
                  ushort_t* __restrict__ C)
{
    __shared__ ushort_t Alds[32][LDA];
    const bool f32 = (*flag == 0);
    const int tid  = threadIdx.x;
    const int wave = tid >> 6;
    const int lane = tid & 63;
    const int quad = lane >> 4;
    const int col  = lane & 15;
    const int mblk = blockIdx.x * 32;

    #pragma unroll
    for (int i = 0; i < 4; ++i) {
        int chunk = i * 512 + tid;
        int row = chunk >> 6;
        int k8  = (chunk & 63) * 8;
        *(bf16x8*)&Alds[row][k8] = load8(emb, (size_t)(mblk + row) * 512 + k8, f32);
    }
    __syncthreads();

    f32x4 acc[2][4];
    #pragma unroll
    for (int r = 0; r < 2; ++r)
        #pragma unroll
        for (int c = 0; c < 4; ++c) acc[r][c] = (f32x4){0.f, 0.f, 0.f, 0.f};

    const int wcol = wave * 64;
    #pragma unroll
    for (int kk = 0; kk < 16; ++kk) {
        bf16x8 a0 = *(const bf16x8*)&Alds[col][kk * 32 + quad * 8];
        bf16x8 a1 = *(const bf16x8*)&Alds[16 + col][kk * 32 + quad * 8];
        #pragma unroll
        for (int c = 0; c < 4; ++c) {
            bf16x8 b = load8(W, (size_t)(wcol + c * 16 + col) * 512 + kk * 32 + quad * 8, f32);
            acc[0][c] = mfma16(a0, b, acc[0][c]);
            acc[1][c] = mfma16(a1, b, acc[1][c]);
        }
    }

    #pragma unroll
    for (int r = 0; r < 2; ++r)
        #pragma unroll
        for (int c = 0; c < 4; ++c)
            #pragma unroll
            for (int g = 0; g < 4; ++g) {
                int m = mblk + r * 16 + quad * 4 + g;
                int n = wcol + c * 16 + col;
                C[(size_t)m * DIM + n] = f2bf(acc[r][c][g] + loadS(bias, n, f32));
            }
}

template <int VT>
__global__ __launch_bounds__(1024)
void attn_fused_kernel(const int* __restrict__ flag, const ushort_t* __restrict__ Q,
                       const void* __restrict__ embOrT, const void* __restrict__ Wv,
                       const void* __restrict__ bv, void* __restrict__ Out)
{
    __shared__ ushort_t Qlds[32][LDA];
    __shared__ ushort_t Plds[2][32][LDP];
    __shared__ float    Lpart[16][32];

    const bool f32 = (*flag == 0);
    const int tid  = threadIdx.x;
    const int wave = tid >> 6;
    const int lane = tid & 63;
    const int quad = lane >> 4;
    const int col  = lane & 15;
    const int q0   = blockIdx.x * 32;

    #pragma unroll
    for (int i = 0; i < 2; ++i) {
        int chunk = i * 1024 + tid;
        int row = chunk >> 6;
        int k8  = (chunk & 63) * 8;
        *(bf16x8*)&Qlds[row][k8] = *(const bf16x8*)&Q[(size_t)(q0 + row) * 512 + k8];
    }
    __syncthreads();

    f32x4 accO[2][2];
    #pragma unroll
    for (int r = 0; r < 2; ++r)
        #pragma unroll
        for (int c = 0; c < 2; ++c) accO[r][c] = (f32x4){0.f, 0.f, 0.f, 0.f};

    float lsum[2][4];
    #pragma unroll
    for (int r = 0; r < 2; ++r)
        #pragma unroll
        for (int g = 0; g < 4; ++g) lsum[r][g] = 0.f;

    const float sc = 0.04419417382415922f * 1.4426950408889634f;
    const int wOcol = wave * 32;

    for (int it = 0; it < 32; ++it) {
        const int j0  = it * 256;
        const int buf = it & 1;

        bf16x8 kb[16];
        const size_t keyrow = (size_t)(j0 + wave * 16 + col) * 512;
        #pragma unroll
        for (int kk = 0; kk < 16; ++kk)
            kb[kk] = *(const bf16x8*)&Q[keyrow + kk * 32 + quad * 8];

        f32x4 accS[2];
        accS[0] = (f32x4){0.f, 0.f, 0.f, 0.f};
        accS[1] = (f32x4){0.f, 0.f, 0.f, 0.f};
        #pragma unroll
        for (int kk = 0; kk < 16; ++kk) {
            bf16x8 a0 = *(const bf16x8*)&Qlds[col][kk * 32 + quad * 8];
            bf16x8 a1 = *(const bf16x8*)&Qlds[16 + col][kk * 32 + quad * 8];
            accS[0] = mfma16(a0, kb[kk], accS[0]);
            accS[1] = mfma16(a1, kb[kk], accS[1]);
        }

        bf16x8 vb[16];
        #pragma unroll
        for (int kk = 0; kk < 8; ++kk)
            #pragma unroll
            for (int c = 0; c < 2; ++c) {
                if (VT) {
                    vb[kk * 2 + c] = *(const bf16x8*)((const ushort_t*)embOrT
                        + (size_t)(wOcol + c * 16 + col) * NTOK + j0 + kk * 32 + quad * 8);
                } else {
                    size_t base = (size_t)(j0 + kk * 32 + quad * 8) * 512 + (wOcol + c * 16 + col);
                    bf16x8 b;
                    if (f32) {
                        const float* bp = (const float*)embOrT + base;
                        #pragma unroll
                        for (int j = 0; j < 8; ++j) b[j] = f2bfh(bp[(size_t)j * 512]);
                    } else {
                        const __bf16* bp = (const __bf16*)embOrT + base;
                        #pragma unroll
                        for (int j = 0; j < 8; ++j) b[j] = bp[(size_t)j * 512];
                    }
                    vb[kk * 2 + c] = b;
                }
            }

        #pragma unroll
        for (int r = 0; r < 2; ++r)
            #pragma unroll
            for (int g = 0; g < 4; ++g) {
                float p = exp2f(fminf(accS[r][g] * sc, 126.0f));
                lsum[r][g] += p;
                Plds[buf][r * 16 + quad * 4 + g][wave * 16 + col] = f2bf(p);
            }

        __syncthreads();

        #pragma unroll
        for (int kk = 0; kk < 8; ++kk) {
            bf16x8 a0 = *(const bf16x8*)&Plds[buf][col][kk * 32 + quad * 8];
            bf16x8 a1 = *(const bf16x8*)&Plds[buf][16 + col][kk * 32 + quad * 8];
            #pragma unroll
            for (int c = 0; c < 2; ++c) {
                accO[0][c] = mfma16(a0, vb[kk * 2 + c], accO[0][c]);
                accO[1][c] = mfma16(a1, vb[kk * 2 + c], accO[1][c]);
            }
        }
    }

    #pragma unroll
    for (int r = 0; r < 2; ++r)
        #pragma unroll
        for (int g = 0; g < 4; ++g) {
            float s = lsum[r][g];
            s += __shfl_xor(s, 1);
            s += __shfl_xor(s, 2);
            s += __shfl_xor(s, 4);
            s += __shfl_xor(s, 8);
            lsum[r][g] = s;
        }
    if (col == 0) {
        #pragma unroll
        for (int r = 0; r < 2; ++r)
            #pragma unroll
            for (int g = 0; g < 4; ++g)
                Lpart[wave][r * 16 + quad * 4 + g] = lsum[r][g];
    }
    __syncthreads();

    #pragma unroll
    for (int r = 0; r < 2; ++r) {
        float rinv[4];
        #pragma unroll
        for (int g = 0; g < 4; ++g) {
            float t = 0.f;
            #pragma unroll
            for (int w = 0; w < 16; ++w) t += Lpart[w][r * 16 + quad * 4 + g];
            rinv[g] = 1.0f / t;
        }
        #pragma unroll
        for (int c = 0; c < 2; ++c)
            #pragma unroll
            for (int g = 0; g < 4; ++g)
                Qlds[r * 16 + quad * 4 + g][wOcol + c * 16 + col] = f2bf(accO[r][c][g] * rinv[g]);
    }
    __syncthreads();

    f32x4 acc2[2][2];
    #pragma unroll
    for (int r = 0; r < 2; ++r)
        #pragma unroll
        for (int c = 0; c < 2; ++c) acc2[r][c] = (f32x4){0.f, 0.f, 0.f, 0.f};

    #pragma unroll
    for (int kk = 0; kk < 16; ++kk) {
        bf16x8 a0 = *(const bf16x8*)&Qlds[col][kk * 32 + quad * 8];
        bf16x8 a1 = *(const bf16x8*)&Qlds[16 + col][kk * 32 + quad * 8];
        #pragma unroll
        for (int c = 0; c < 2; ++c) {
            bf16x8 b = load8(Wv, (size_t)(wOcol + c * 16 + col) * 512 + kk * 32 + quad * 8, f32);
            acc2[0][c] = mfma16(a0, b, acc2[0][c]);
            acc2[1][c] = mfma16(a1, b, acc2[1][c]);
        }
    }

    #pragma unroll
    for (int r = 0; r < 2; ++r)
        #pragma unroll
        for (int c = 0; c < 2; ++c)
            #pragma unroll
            for (int g = 0; g < 4; ++g) {
                int m = q0 + r * 16 + quad * 4 + g;
                int n = wOcol + c * 16 + col;
                float v = acc2[r][c][g] + loadS(bv, n, f32);
                if (f32) ((float*)Out)[(size_t)m * DIM + n] = v;
                else     ((ushort_t*)Out)[(size_t)m * DIM + n] = f2bf(v);
            }
}

extern "C" void kernel_launch(void* const* d_in, const int* in_sizes, int n_in,
                              void* d_out, int out_size, void* d_ws, size_t ws_size,
                              hipStream_t stream)
{
    const void* emb = d_in[0];
    const void* Wqk = d_in[1];
    const void* bqk = d_in[2];
    const void* Wv  = d_in[3];
    const void* bv  = d_in[4];

    char* W = (char*)d_ws;
    int*      flag  = (int*)W;
    float*    lsumA = (float*)(W + 64);                        // 4x8192 fp32 = 128 KB
    ushort_t* Wqkb  = (ushort_t*)(W + 64 + 131072);            // 512 KB
    ushort_t* Wvb   = Wqkb + (size_t)DIM * DIM;                // 512 KB
    ushort_t* bqkb  = Wvb + (size_t)DIM * DIM;                 // 1 KB
    ushort_t* bvb   = bqkb + DIM;                              // 1 KB
    ushort_t* embT  = bvb + DIM;                               // 8 MB
    ushort_t* Qws   = embT + (size_t)DIM * NTOK;               // 8 MB
    ushort_t* Pall  = Qws + (size_t)DIM * NTOK;                // 4 x 8 MB bf16

    const size_t needA = 64 + 131072 + 2 * (size_t)DIM * DIM * 2 + 2 * DIM * 2
                       + 6 * (size_t)NTOK * DIM * 2;           // ~51.5 MB (ws>=64MB proven)
    const size_t needB = 64 + 2 * (size_t)NTOK * DIM * 2;      // 16.03 MB

    detect_kernel<<<dim3(1), dim3(64), 0, stream>>>((const ushort_t*)emb, flag);

    if (ws_size >= needA) {
        prep_kernel<<<dim3(128), dim3(256), 0, stream>>>(flag, Wqk, bqk, Wv, bv,
                                                         Wqkb, bqkb, Wvb, bvb);
        projqT_kernel<<<dim3(NTOK / 64), dim3(512), 0, stream>>>(flag, emb, Wqkb, bqkb,
                                                                 Qws, embT);
        attn128_kernel<<<dim3(256), dim3(512), 0, stream>>>(Qws, embT, Pall, lsumA);
        finalize_kernel<<<dim3(NTOK / 64), dim3(512), 0, stream>>>(flag, Pall, lsumA,
                                                                   Wqkb == nullptr ? nullptr : Wvb, bvb, d_out);
    } else if (ws_size >= needB) {
        ushort_t* embT2 = (ushort_t*)(W + 64);
        ushort_t* Qws2  = embT2 + (size_t)DIM * NTOK;
        transpose_kernel<<<dim3(128, 8), dim3(256), 0, stream>>>(flag, emb, embT2);
        projq_kernel<<<dim3(NTOK / 32), dim3(512), 0, stream>>>(flag, emb, Wqk, bqk, Qws2);
        attn_fused_kernel<1><<<dim3(NTOK / 32), dim3(1024), 0, stream>>>(
            flag, Qws2, embT2, Wv, bv, d_out);
    } else {
        ushort_t* Qsm = (ushort_t*)(W + 64);
        projq_kernel<<<dim3(NTOK / 32), dim3(512), 0, stream>>>(flag, emb, Wqk, bqk, Qsm);
        attn_fused_kernel<0><<<dim3(NTOK / 32), dim3(1024), 0, stream>>>(
            flag, Qsm, emb, Wv, bv, d_out);
    }
}

// Round 16
// 383.728 us; speedup vs baseline: 2.0047x; 2.0047x over previous
//
#include <hip/hip_runtime.h>
#include <hip/hip_bf16.h>

// N=8192, D=512.  Q = emb@Wqk^T+bqk (K==Q); out = softmax(QK^T/sqrt(512)) @ V.
// Softmax rows sum to 1 => out = (softmax(S)@emb) @ Wv^T + bv (V never built).
// Device dtype runtime-detected (fp32 observed). Internal: bf16 MFMA, fp32 acc.
// R15 post-mortem: Tq=128 spills on THREE structurally different attempts
// (R9/R12/R15) -- the unified-file allocator will not hold accO[8][4]+working
// set regardless of launch_bounds. Tq=64's 2.05GB @ ~7.2TB/s (285us) is the
// practical attention floor. R16 = R14 verbatim (best: 383us total).

#define NTOK 8192
#define DIM  512

typedef unsigned short ushort_t;
typedef __attribute__((ext_vector_type(8))) __bf16 bf16x8;
typedef __attribute__((ext_vector_type(4))) float f32x4;

__device__ __forceinline__ float bf2f(ushort_t u) {
    union { unsigned int i; float f; } v; v.i = ((unsigned int)u) << 16; return v.f;
}
__device__ __forceinline__ ushort_t f2bf(float f) {
    union { float f; unsigned int i; } v; v.f = f;
    unsigned int b = v.i;
    return (ushort_t)((b + 0x7FFFu + ((b >> 16) & 1u)) >> 16);   // RNE
}
__device__ __forceinline__ __bf16 f2bfh(float f) {
    union { ushort_t u; __bf16 h; } c; c.u = f2bf(f); return c.h;
}
__device__ __forceinline__ f32x4 mfma16(bf16x8 a, bf16x8 b, f32x4 c) {
    return __builtin_amdgcn_mfma_f32_16x16x32_bf16(a, b, c, 0, 0, 0);
}
__device__ __forceinline__ bf16x8 load8(const void* p, size_t idx, bool f32) {
    if (f32) {
        const float* f = (const float*)p + idx;
        bf16x8 r;
        #pragma unroll
        for (int j = 0; j < 8; ++j) r[j] = f2bfh(f[j]);
        return r;
    }
    return *(const bf16x8*)((const ushort_t*)p + idx);
}
__device__ __forceinline__ float loadS(const void* p, size_t idx, bool f32) {
    return f32 ? ((const float*)p)[idx] : bf2f(((const ushort_t*)p)[idx]);
}

#define LDA 520   // 260 dw, %32=4: uniform 2 dw/bank for b128 row reads
#define LDP 264

// ---------------------------------------------------------------------------
// Dtype probe: flag=1 => bf16 data, flag=0 => fp32.
// ---------------------------------------------------------------------------
__global__ void detect_kernel(const ushort_t* __restrict__ emb, int* __restrict__ flag)
{
    int lane = threadIdx.x;
    int cnt = 0;
    #pragma unroll
    for (int i = 0; i < 8; ++i) {
        ushort_t u = emb[(size_t)(lane * 8 + i) * 2];
        int a = u & 0x7FFF;
        int e = (u >> 7) & 0xFF;
        if (a == 0 || (e >= 111 && e <= 143)) cnt++;
    }
    cnt += __shfl_xor(cnt, 1);  cnt += __shfl_xor(cnt, 2);  cnt += __shfl_xor(cnt, 4);
    cnt += __shfl_xor(cnt, 8);  cnt += __shfl_xor(cnt, 16); cnt += __shfl_xor(cnt, 32);
    if (lane == 0) *flag = (cnt >= 460) ? 1 : 0;
}

// ---------------------------------------------------------------------------
// Prep: convert Wqk, Wv (512x512) + bqk, bv (512) to bf16 in ws.
// ---------------------------------------------------------------------------
__global__ __launch_bounds__(256)
void prep_kernel(const int* __restrict__ flag,
                 const void* __restrict__ Wqk, const void* __restrict__ bqk,
                 const void* __restrict__ Wv,  const void* __restrict__ bv,
                 ushort_t* __restrict__ Wqkb, ushort_t* __restrict__ bqkb,
                 ushort_t* __restrict__ Wvb,  ushort_t* __restrict__ bvb)
{
    const bool f32 = (*flag == 0);
    size_t gid = (size_t)blockIdx.x * 256 + threadIdx.x;
    size_t base = gid * 8;
    *(bf16x8*)&Wqkb[base] = load8(Wqk, base, f32);
    *(bf16x8*)&Wvb[base]  = load8(Wv,  base, f32);
    if (gid < 64) {
        *(bf16x8*)&bqkb[base] = load8(bqk, base, f32);
        *(bf16x8*)&bvb[base]  = load8(bv,  base, f32);
    }
}

// ---------------------------------------------------------------------------
// Fused: Q[64 rows] = emb@Wqk^T+bqk AND embT columns, from one staged tile.
// 128 blocks x 512 thr (8 waves); wave w owns out cols [64w,64w+64).
// ---------------------------------------------------------------------------
__global__ __launch_bounds__(512)
void projqT_kernel(const int* __restrict__ flag, const void* __restrict__ emb,
                   const ushort_t* __restrict__ Wb, const ushort_t* __restrict__ bb,
                   ushort_t* __restrict__ C, ushort_t* __restrict__ embT)
{
    __shared__ ushort_t Alds[64][LDA];   // 66,560 B
    const bool f32 = (*flag == 0);
    const int tid  = threadIdx.x;
    const int wave = tid >> 6;
    const int lane = tid & 63;
    const int quad = lane >> 4;
    const int col  = lane & 15;
    const int mblk = blockIdx.x * 64;

    #pragma unroll
    for (int i = 0; i < 8; ++i) {
        int chunk = i * 512 + tid;
        int row = chunk >> 6;
        int k8  = (chunk & 63) * 8;
        *(bf16x8*)&Alds[row][k8] = load8(emb, (size_t)(mblk + row) * 512 + k8, f32);
    }
    __syncthreads();

    // ---- transpose store: thread t owns dim t, 64 tokens (128 B) ----
    {
        ushort_t buf[64];
        #pragma unroll
        for (int r = 0; r < 64; ++r) buf[r] = Alds[r][tid];
        ushort_t* dst = embT + (size_t)tid * NTOK + mblk;
        #pragma unroll
        for (int i = 0; i < 8; ++i)
            *(uint4*)(dst + i * 8) = *(uint4*)&buf[i * 8];
    }

    // ---- Q projection (64 rows x this wave's 64 cols) ----
    f32x4 acc[4][4];
    #pragma unroll
    for (int r = 0; r < 4; ++r)
        #pragma unroll
        for (int c = 0; c < 4; ++c) acc[r][c] = (f32x4){0.f, 0.f, 0.f, 0.f};

    const int wcol = wave * 64;
    #pragma unroll
    for (int kk = 0; kk < 16; ++kk) {
        bf16x8 a[4];
        #pragma unroll
        for (int r = 0; r < 4; ++r)
            a[r] = *(const bf16x8*)&Alds[r * 16 + col][kk * 32 + quad * 8];
        #pragma unroll
        for (int c = 0; c < 4; ++c) {
            bf16x8 b = *(const bf16x8*)&Wb[(size_t)(wcol + c * 16 + col) * 512
                                           + kk * 32 + quad * 8];
            #pragma unroll
            for (int r = 0; r < 4; ++r)
                acc[r][c] = mfma16(a[r], b, acc[r][c]);
        }
    }

    #pragma unroll
    for (int r = 0; r < 4; ++r)
        #pragma unroll
        for (int c = 0; c < 4; ++c)
            #pragma unroll
            for (int g = 0; g < 4; ++g) {
                int m = mblk + r * 16 + quad * 4 + g;
                int n = wcol + c * 16 + col;
                C[(size_t)m * DIM + n] = f2bf(acc[r][c][g] + bf2f(bb[n]));
            }
}

// ---------------------------------------------------------------------------
// Attention partials (R13-proven, unchanged): 256 blocks = 128 q-tiles (Tq=64)
// x 2 key-halves, 1024 thr = 16 waves, KT=256 (16 iters), dbuf Plds.
// ---------------------------------------------------------------------------
__global__ __launch_bounds__(1024)
void attn64_kernel(const ushort_t* __restrict__ Q, const ushort_t* __restrict__ embT,
                   ushort_t* __restrict__ P0, ushort_t* __restrict__ P1,
                   float* __restrict__ lsumA)
{
    __shared__ ushort_t Qlds[64][LDA];
    __shared__ ushort_t Plds[2][64][LDP];
    __shared__ float    Lp[16][64];

    const int tid  = threadIdx.x;
    const int wave = tid >> 6;
    const int lane = tid & 63;
    const int quad = lane >> 4;
    const int col  = lane & 15;
    const int qt   = blockIdx.x & 127;
    const int ks   = blockIdx.x >> 7;
    const int q0   = qt * 64;
    const int kbase = ks * 4096;
    ushort_t* Ps = ks ? P1 : P0;

    #pragma unroll
    for (int i = 0; i < 4; ++i) {
        int chunk = i * 1024 + tid;
        int row = chunk >> 6;
        int k8  = (chunk & 63) * 8;
        *(bf16x8*)&Qlds[row][k8] = *(const bf16x8*)&Q[(size_t)(q0 + row) * 512 + k8];
    }
    __syncthreads();

    f32x4 accO[4][2];
    #pragma unroll
    for (int r = 0; r < 4; ++r)
        #pragma unroll
        for (int c = 0; c < 2; ++c) accO[r][c] = (f32x4){0.f, 0.f, 0.f, 0.f};

    float lsum[4][4];
    #pragma unroll
    for (int r = 0; r < 4; ++r)
        #pragma unroll
        for (int g = 0; g < 4; ++g) lsum[r][g] = 0.f;

    const float sc = 0.04419417382415922f * 1.4426950408889634f;  // 1/sqrt(512)*log2e
    const int wd = wave * 32;

    for (int it = 0; it < 16; ++it) {
        const int j0  = kbase + it * 256;
        const int buf = it & 1;

        f32x4 accS[4];
        #pragma unroll
        for (int r = 0; r < 4; ++r) accS[r] = (f32x4){0.f, 0.f, 0.f, 0.f};
        const size_t keyrow = (size_t)(j0 + wave * 16 + col) * 512;
        #pragma unroll
        for (int h = 0; h < 2; ++h) {
            bf16x8 kb[8];
            #pragma unroll
            for (int kk = 0; kk < 8; ++kk)
                kb[kk] = *(const bf16x8*)&Q[keyrow + (h * 8 + kk) * 32 + quad * 8];
            #pragma unroll
            for (int kk = 0; kk < 8; ++kk) {
                const int cofs = (h * 8 + kk) * 32 + quad * 8;
                #pragma unroll
                for (int r = 0; r < 4; ++r) {
                    bf16x8 a = *(const bf16x8*)&Qlds[r * 16 + col][cofs];
                    accS[r] = mfma16(a, kb[kk], accS[r]);
                }
            }
        }

        bf16x8 vbA[8];
        #pragma unroll
        for (int kk = 0; kk < 4; ++kk)
            #pragma unroll
            for (int c = 0; c < 2; ++c)
                vbA[kk * 2 + c] = *(const bf16x8*)&embT[
                    (size_t)(wd + c * 16 + col) * NTOK + j0 + kk * 32 + quad * 8];

        #pragma unroll
        for (int r = 0; r < 4; ++r)
            #pragma unroll
            for (int g = 0; g < 4; ++g) {
                float p = exp2f(fminf(accS[r][g] * sc, 126.0f));
                lsum[r][g] += p;
                Plds[buf][r * 16 + quad * 4 + g][wave * 16 + col] = f2bf(p);
            }

        bf16x8 vbB[8];
        #pragma unroll
        for (int kk = 0; kk < 4; ++kk)
            #pragma unroll
            for (int c = 0; c < 2; ++c)
                vbB[kk * 2 + c] = *(const bf16x8*)&embT[
                    (size_t)(wd + c * 16 + col) * NTOK + j0 + (4 + kk) * 32 + quad * 8];

        __syncthreads();   // P(t) visible; buf reuse at distance 2 safe

        #pragma unroll
        for (int kk = 0; kk < 4; ++kk) {
            #pragma unroll
            for (int r = 0; r < 4; ++r) {
                bf16x8 a = *(const bf16x8*)&Plds[buf][r * 16 + col][kk * 32 + quad * 8];
                #pragma unroll
                for (int c = 0; c < 2; ++c)
                    accO[r][c] = mfma16(a, vbA[kk * 2 + c], accO[r][c]);
            }
        }
        #pragma unroll
        for (int kk = 0; kk < 4; ++kk) {
            #pragma unroll
            for (int r = 0; r < 4; ++r) {
                bf16x8 a = *(const bf16x8*)&Plds[buf][r * 16 + col][(4 + kk) * 32 + quad * 8];
                #pragma unroll
                for (int c = 0; c < 2; ++c)
                    accO[r][c] = mfma16(a, vbB[kk * 2 + c], accO[r][c]);
            }
        }
    }

    #pragma unroll
    for (int r = 0; r < 4; ++r)
        #pragma unroll
        for (int g = 0; g < 4; ++g) {
            float s = lsum[r][g];
            s += __shfl_xor(s, 1);
            s += __shfl_xor(s, 2);
            s += __shfl_xor(s, 4);
            s += __shfl_xor(s, 8);
            if (col == 0)
                Lp[wave][r * 16 + quad * 4 + g] = s;
        }
    __syncthreads();
    if (tid < 64) {
        float t = 0.f;
        #pragma unroll
        for (int w = 0; w < 16; ++w) t += Lp[w][tid];
        lsumA[(size_t)ks * NTOK + q0 + tid] = t;
    }

    #pragma unroll
    for (int r = 0; r < 4; ++r)
        #pragma unroll
        for (int c = 0; c < 2; ++c)
            #pragma unroll
            for (int g = 0; g < 4; ++g)
                Ps[(size_t)(q0 + r * 16 + quad * 4 + g) * DIM + wd + c * 16 + col]
                    = f2bf(accO[r][c][g]);
}

// ---------------------------------------------------------------------------
// Finalize64: T = (P0+P1)/(l0+l1), out = T @ Wv^T + bv (bf16 weights).
// 128 blocks x 512 thr, 64 rows/block.
// ---------------------------------------------------------------------------
__global__ __launch_bounds__(512)
void finalize_kernel(const int* __restrict__ flag,
                     const ushort_t* __restrict__ P0, const ushort_t* __restrict__ P1,
                     const float* __restrict__ lsumA,
                     const ushort_t* __restrict__ Wb, const ushort_t* __restrict__ bb,
                     void* __restrict__ Out)
{
    __shared__ ushort_t Alds[64][LDA];
    const bool f32 = (*flag == 0);
    const int tid  = threadIdx.x;
    const int wave = tid >> 6;
    const int lane = tid & 63;
    const int quad = lane >> 4;
    const int col  = lane & 15;
    const int mblk = blockIdx.x * 64;

    #pragma unroll
    for (int i = 0; i < 8; ++i) {
        int chunk = i * 512 + tid;
        int row = chunk >> 6;
        int k8  = (chunk & 63) * 8;
        int m   = mblk + row;
        float rv = 1.0f / (lsumA[m] + lsumA[NTOK + m]);
        bf16x8 v0 = *(const bf16x8*)&P0[(size_t)m * 512 + k8];
        bf16x8 v1 = *(const bf16x8*)&P1[(size_t)m * 512 + k8];
        bf16x8 t;
        #pragma unroll
        for (int j = 0; j < 8; ++j) t[j] = f2bfh(((float)v0[j] + (float)v1[j]) * rv);
        *(bf16x8*)&Alds[row][k8] = t;
    }
    __syncthreads();

    f32x4 acc[4][4];
    #pragma unroll
    for (int r = 0; r < 4; ++r)
        #pragma unroll
        for (int c = 0; c < 4; ++c) acc[r][c] = (f32x4){0.f, 0.f, 0.f, 0.f};

    const int wcol = wave * 64;
    #pragma unroll
    for (int kk = 0; kk < 16; ++kk) {
        bf16x8 a[4];
        #pragma unroll
        for (int r = 0; r < 4; ++r)
            a[r] = *(const bf16x8*)&Alds[r * 16 + col][kk * 32 + quad * 8];
        #pragma unroll
        for (int c = 0; c < 4; ++c) {
            bf16x8 b = *(const bf16x8*)&Wb[(size_t)(wcol + c * 16 + col) * 512
                                           + kk * 32 + quad * 8];
            #pragma unroll
            for (int r = 0; r < 4; ++r)
                acc[r][c] = mfma16(a[r], b, acc[r][c]);
        }
    }

    #pragma unroll
    for (int r = 0; r < 4; ++r)
        #pragma unroll
        for (int c = 0; c < 4; ++c)
            #pragma unroll
            for (int g = 0; g < 4; ++g) {
                int m = mblk + r * 16 + quad * 4 + g;
                int n = wcol + c * 16 + col;
                float v = acc[r][c][g] + bf2f(bb[n]);
                if (f32) ((float*)Out)[(size_t)m * DIM + n] = v;
                else     ((ushort_t*)Out)[(size_t)m * DIM + n] = f2bf(v);
            }
}

// ---------------------------------------------------------------------------
// Fallback kernels (R13-proven) for smaller workspaces.
// ---------------------------------------------------------------------------
__global__ __launch_bounds__(256)
void transpose_kernel(const int* __restrict__ flag, const void* __restrict__ emb,
                      ushort_t* __restrict__ embT)
{
    __shared__ float tile[64][65];
    const bool f32 = (*flag == 0);
    const int t  = threadIdx.x;
    const int j0 = blockIdx.x * 64;
    const int d0 = blockIdx.y * 64;
    {
        int r = t >> 2, cs = (t & 3) * 16;
        if (f32) {
            const float* src = (const float*)emb + (size_t)(j0 + r) * DIM + d0 + cs;
            #pragma unroll
            for (int i = 0; i < 16; i += 4) {
                float4 v = *(const float4*)(src + i);
                tile[r][cs + i]     = v.x;
                tile[r][cs + i + 1] = v.y;
                tile[r][cs + i + 2] = v.z;
                tile[r][cs + i + 3] = v.w;
            }
        } else {
            const ushort_t* src = (const ushort_t*)emb + (size_t)(j0 + r) * DIM + d0 + cs;
            #pragma unroll
            for (int i = 0; i < 16; ++i) tile[r][cs + i] = bf2f(src[i]);
        }
    }
    __syncthreads();
    {
        int d = t >> 2, js = (t & 3) * 16;
        ushort_t buf[16];
        #pragma unroll
        for (int i = 0; i < 16; ++i) buf[i] = f2bf(tile[js + i][d]);
        ushort_t* dst = embT + (size_t)(d0 + d) * NTOK + j0 + js;
        *(uint4*)dst       = *(uint4*)&buf[0];
        *(uint4*)(dst + 8) = *(uint4*)&buf[8];
    }
}

__global__ __launch_bounds__(512)
void projq_kernel(const int* __restrict__ flag, const void* __restrict__ emb,
                  const void* __restrict__ W, const void* __restrict__ bias,
                  ushort_t* __restrict__ C)
{
    __shared__ ushort_t Alds[32][LDA];
    const bool f32 = (*flag == 0);
    const int tid  = threadIdx.x;
    const int wave = tid >> 6;
    const int lane = tid & 63;
    const int quad = lane >> 4;
    const int col  = lane & 15;
    const int mblk = blockIdx.x * 32;

    #pragma unroll
    for (int i = 0; i < 4; ++i) {
        int chunk = i * 512 + tid;
        int row = chunk >> 6;
        int k8  = (chunk & 63) * 8;
        *(bf16x8*)&Alds[row][k8] = load8(emb, (size_t)(mblk + row) * 512 + k8, f32);
    }
    __syncthreads();

    f32x4 acc[2][4];
    #pragma unroll
    for (int r = 0; r < 2; ++r)
        #pragma unroll
        for (int c = 0; c < 4; ++c) acc[r][c] = (f32x4){0.f, 0.f, 0.f, 0.f};

    const int wcol = wave * 64;
    #pragma unroll
    for (int kk = 0; kk < 16; ++kk) {
        bf16x8 a0 = *(const bf16x8*)&Alds[col][kk * 32 + quad * 8];
        bf16x8 a1 = *(const bf16x8*)&Alds[16 + col][kk * 32 + quad * 8];
        #pragma unroll
        for (int c = 0; c < 4; ++c) {
            bf16x8 b = load8(W, (size_t)(wcol + c * 16 + col) * 512 + kk * 32 + quad * 8, f32);
            acc[0][c] = mfma16(a0, b, acc[0][c]);
            acc[1][c] = mfma16(a1, b, acc[1][c]);
        }
    }

    #pragma unroll
    for (int r = 0; r < 2; ++r)
        #pragma unroll
        for (int c = 0; c < 4; ++c)
            #pragma unroll
            for (int g = 0; g < 4; ++g) {
                int m = mblk + r * 16 + quad * 4 + g;
                int n = wcol + c * 16 + col;
                C[(size_t)m * DIM + n] = f2bf(acc[r][c][g] + loadS(bias, n, f32));
            }
}

template <int VT>
__global__ __launch_bounds__(1024)
void attn_fused_kernel(const int* __restrict__ flag, const ushort_t* __restrict__ Q,
                       const void* __restrict__ embOrT, const void* __restrict__ Wv,
                       const void* __restrict__ bv, void* __restrict__ Out)
{
    __shared__ ushort_t Qlds[32][LDA];
    __shared__ ushort_t Plds[2][32][LDP];
    __shared__ float    Lpart[16][32];

    const bool f32 = (*flag == 0);
    const int tid  = threadIdx.x;
    const int wave = tid >> 6;
    const int lane = tid & 63;
    const int quad = lane >> 4;
    const int col  = lane & 15;
    const int q0   = blockIdx.x * 32;

    #pragma unroll
    for (int i = 0; i < 2; ++i) {
        int chunk = i * 1024 + tid;
        int row = chunk >> 6;
        int k8  = (chunk & 63) * 8;
        *(bf16x8*)&Qlds[row][k8] = *(const bf16x8*)&Q[(size_t)(q0 + row) * 512 + k8];
    }
    __syncthreads();

    f32x4 accO[2][2];
    #pragma unroll
    for (int r = 0; r < 2; ++r)
        #pragma unroll
        for (int c = 0; c < 2; ++c) accO[r][c] = (f32x4){0.f, 0.f, 0.f, 0.f};

    float lsum[2][4];
    #pragma unroll
    for (int r = 0; r < 2; ++r)
        #pragma unroll
        for (int g = 0; g < 4; ++g) lsum[r][g] = 0.f;

    const float sc = 0.04419417382415922f * 1.4426950408889634f;
    const int wOcol = wave * 32;

    for (int it = 0; it < 32; ++it) {
        const int j0  = it * 256;
        const int buf = it & 1;

        bf16x8 kb[16];
        const size_t keyrow = (size_t)(j0 + wave * 16 + col) * 512;
        #pragma unroll
        for (int kk = 0; kk < 16; ++kk)
            kb[kk] = *(const bf16x8*)&Q[keyrow + kk * 32 + quad * 8];

        f32x4 accS[2];
        accS[0] = (f32x4){0.f, 0.f, 0.f, 0.f};
        accS[1] = (f32x4){0.f, 0.f, 0.f, 0.f};
        #pragma unroll
        for (int kk = 0; kk < 16; ++kk) {
            bf16x8 a0 = *(const bf16x8*)&Qlds[col][kk * 32 + quad * 8];
            bf16x8 a1 = *(const bf16x8*)&Qlds[16 + col][kk * 32 + quad * 8];
            accS[0] = mfma16(a0, kb[kk], accS[0]);
            accS[1] = mfma16(a1, kb[kk], accS[1]);
        }

        bf16x8 vb[16];
        #pragma unroll
        for (int kk = 0; kk < 8; ++kk)
            #pragma unroll
            for (int c = 0; c < 2; ++c) {
                if (VT) {
                    vb[kk * 2 + c] = *(const bf16x8*)((const ushort_t*)embOrT
                        + (size_t)(wOcol + c * 16 + col) * NTOK + j0 + kk * 32 + quad * 8);
                } else {
                    size_t base = (size_t)(j0 + kk * 32 + quad * 8) * 512 + (wOcol + c * 16 + col);
                    bf16x8 b;
                    if (f32) {
                        const float* bp = (const float*)embOrT + base;
                        #pragma unroll
                        for (int j = 0; j < 8; ++j) b[j] = f2bfh(bp[(size_t)j * 512]);
                    } else {
                        const __bf16* bp = (const __bf16*)embOrT + base;
                        #pragma unroll
                        for (int j = 0; j < 8; ++j) b[j] = bp[(size_t)j * 512];
                    }
                    vb[kk * 2 + c] = b;
                }
            }

        #pragma unroll
        for (int r = 0; r < 2; ++r)
            #pragma unroll
            for (int g = 0; g < 4; ++g) {
                float p = exp2f(fminf(accS[r][g] * sc, 126.0f));
                lsum[r][g] += p;
                Plds[buf][r * 16 + quad * 4 + g][wave * 16 + col] = f2bf(p);
            }

        __syncthreads();

        #pragma unroll
        for (int kk = 0; kk < 8; ++kk) {
            bf16x8 a0 = *(const bf16x8*)&Plds[buf][col][kk * 32 + quad * 8];
            bf16x8 a1 = *(const bf16x8*)&Plds[buf][16 + col][kk * 32 + quad * 8];
            #pragma unroll
            for (int c = 0; c < 2; ++c) {
                accO[0][c] = mfma16(a0, vb[kk * 2 + c], accO[0][c]);
                accO[1][c] = mfma16(a1, vb[kk * 2 + c], accO[1][c]);
            }
        }
    }

    #pragma unroll
    for (int r = 0; r < 2; ++r)
        #pragma unroll
        for (int g = 0; g < 4; ++g) {
            float s = lsum[r][g];
            s += __shfl_xor(s, 1);
            s += __shfl_xor(s, 2);
            s += __shfl_xor(s, 4);
            s += __shfl_xor(s, 8);
            lsum[r][g] = s;
        }
    if (col == 0) {
        #pragma unroll
        for (int r = 0; r < 2; ++r)
            #pragma unroll
            for (int g = 0; g < 4; ++g)
                Lpart[wave][r * 16 + quad * 4 + g] = lsum[r][g];
    }
    __syncthreads();

    #pragma unroll
    for (int r = 0; r < 2; ++r) {
        float rinv[4];
        #pragma unroll
        for (int g = 0; g < 4; ++g) {
            float t = 0.f;
            #pragma unroll
            for (int w = 0; w < 16; ++w) t += Lpart[w][r * 16 + quad * 4 + g];
            rinv[g] = 1.0f / t;
        }
        #pragma unroll
        for (int c = 0; c < 2; ++c)
            #pragma unroll
            for (int g = 0; g < 4; ++g)
                Qlds[r * 16 + quad * 4 + g][wOcol + c * 16 + col] = f2bf(accO[r][c][g] * rinv[g]);
    }
    __syncthreads();

    f32x4 acc2[2][2];
    #pragma unroll
    for (int r = 0; r < 2; ++r)
        #pragma unroll
        for (int c = 0; c < 2; ++c) acc2[r][c] = (f32x4){0.f, 0.f, 0.f, 0.f};

    #pragma unroll
    for (int kk = 0; kk < 16; ++kk) {
        bf16x8 a0 = *(const bf16x8*)&Qlds[col][kk * 32 + quad * 8];
        bf16x8 a1 = *(const bf16x8*)&Qlds[16 + col][kk * 32 + quad * 8];
        #pragma unroll
        for (int c = 0; c < 2; ++c) {
            bf16x8 b = load8(Wv, (size_t)(wOcol + c * 16 + col) * 512 + kk * 32 + quad * 8, f32);
            acc2[0][c] = mfma16(a0, b, acc2[0][c]);
            acc2[1][c] = mfma16(a1, b, acc2[1][c]);
        }
    }

    #pragma unroll
    for (int r = 0; r < 2; ++r)
        #pragma unroll
        for (int c = 0; c < 2; ++c)
            #pragma unroll
            for (int g = 0; g < 4; ++g) {
                int m = q0 + r * 16 + quad * 4 + g;
                int n = wOcol + c * 16 + col;
                float v = acc2[r][c][g] + loadS(bv, n, f32);
                if (f32) ((float*)Out)[(size_t)m * DIM + n] = v;
                else     ((ushort_t*)Out)[(size_t)m * DIM + n] = f2bf(v);
            }
}

extern "C" void kernel_launch(void* const* d_in, const int* in_sizes, int n_in,
                              void* d_out, int out_size, void* d_ws, size_t ws_size,
                              hipStream_t stream)
{
    const void* emb = d_in[0];
    const void* Wqk = d_in[1];
    const void* bqk = d_in[2];
    const void* Wv  = d_in[3];
    const void* bv  = d_in[4];

    char* W = (char*)d_ws;
    int*      flag  = (int*)W;
    float*    lsumA = (float*)(W + 64);                        // 64 KB
    ushort_t* Wqkb  = (ushort_t*)(W + 64 + 65536);             // 512 KB
    ushort_t* Wvb   = Wqkb + (size_t)DIM * DIM;                // 512 KB
    ushort_t* bqkb  = Wvb + (size_t)DIM * DIM;                 // 1 KB
    ushort_t* bvb   = bqkb + DIM;                              // 1 KB
    ushort_t* embT  = bvb + DIM;                               // 8 MB
    ushort_t* Qws   = embT + (size_t)DIM * NTOK;               // 8 MB
    ushort_t* P0    = Qws + (size_t)DIM * NTOK;                // 8 MB
    ushort_t* P1    = P0 + (size_t)NTOK * DIM;                 // 8 MB

    const size_t needA = 64 + 65536 + 2 * (size_t)DIM * DIM * 2 + 2 * DIM * 2
                       + 4 * (size_t)NTOK * DIM * 2;           // ~33.1 MB
    const size_t needB = 64 + 2 * (size_t)NTOK * DIM * 2;      // 16.03 MB

    detect_kernel<<<dim3(1), dim3(64), 0, stream>>>((const ushort_t*)emb, flag);

    if (ws_size >= needA) {
        prep_kernel<<<dim3(128), dim3(256), 0, stream>>>(flag, Wqk, bqk, Wv, bv,
                                                         Wqkb, bqkb, Wvb, bvb);
        projqT_kernel<<<dim3(NTOK / 64), dim3(512), 0, stream>>>(flag, emb, Wqkb, bqkb,
                                                                 Qws, embT);
        attn64_kernel<<<dim3(256), dim3(1024), 0, stream>>>(Qws, embT, P0, P1, lsumA);
        finalize_kernel<<<dim3(NTOK / 64), dim3(512), 0, stream>>>(flag, P0, P1, lsumA,
                                                                   Wvb, bvb, d_out);
    } else if (ws_size >= needB) {
        ushort_t* embT2 = (ushort_t*)(W + 64);
        ushort_t* Qws2  = embT2 + (size_t)DIM * NTOK;
        transpose_kernel<<<dim3(128, 8), dim3(256), 0, stream>>>(flag, emb, embT2);
        projq_kernel<<<dim3(NTOK / 32), dim3(512), 0, stream>>>(flag, emb, Wqk, bqk, Qws2);
        attn_fused_kernel<1><<<dim3(NTOK / 32), dim3(1024), 0, stream>>>(
            flag, Qws2, embT2, Wv, bv, d_out);
    } else {
        ushort_t* Qsm = (ushort_t*)(W + 64);
        projq_kernel<<<dim3(NTOK / 32), dim3(512), 0, stream>>>(flag, emb, Wqk, bqk, Qsm);
        attn_fused_kernel<0><<<dim3(NTOK / 32), dim3(1024), 0, stream>>>(
            flag, Qsm, emb, Wv, bv, d_out);
    }
}